// Round 2
// baseline (3458.399 us; speedup 1.0000x reference)
//
#include <hip/hip_runtime.h>
#include <math.h>

// ODE-RNN forward: B=512, K=1024, U=16, P=32, H=128, L=32, TD=64
// Strategy: 256 blocks x 512 threads; block handles 2 batch elements.
// Gate weights [w_ih | w_hh] (384x160) register-resident: thread t owns
// rows {j, j+128, j+256} (r/z/n of hidden unit j=t&127) x 40-col slice
// (q=t>>7). Activation vec [x(32)|h(128)] in LDS, broadcast reads.
// head_W register-resident (16/thread). lift_W/u2y in LDS (tiny).

// NOTE: macro param must NOT be named `w` — (v).w would be captured.
#define DOT4(acc, v, arr, base)                                           \
  acc += (v).x * (arr)[(base)] + (v).y * (arr)[(base) + 1] +              \
         (v).z * (arr)[(base) + 2] + (v).w * (arr)[(base) + 3];

__device__ __forceinline__ float sigf(float x) {
  return 1.0f / (1.0f + __expf(-x));
}

__device__ __forceinline__ float tanh_fast(float x) {
  float ax = fabsf(x);
  float e = __expf(2.0f * ax);
  float r = 1.0f - 2.0f / (e + 1.0f);
  return copysignf(r, x);
}

extern "C" __global__ __launch_bounds__(512, 2) void odernn_kernel(
    const float* __restrict__ y0, const float* __restrict__ u_seq,
    const float* __restrict__ dt_seq, const float* __restrict__ y_seq,
    const float* __restrict__ u2y, const float* __restrict__ lift_W,
    const float* __restrict__ lift_b, const float* __restrict__ w_ih,
    const float* __restrict__ w_hh, const float* __restrict__ b_ih,
    const float* __restrict__ b_hh, const float* __restrict__ head_W,
    const float* __restrict__ head_b, const int* __restrict__ tf_p,
    float* __restrict__ out_ys, float* __restrict__ out_th) {
  __shared__ __align__(16) float vecL[2][160];   // [x(32) | h(128)] per batch
  __shared__ __align__(16) float featL[2][48];   // [u(16) | y_in(32)]
  __shared__ float gpart[3][2][3][128];          // q=1..3 partials, r/z/hn
  __shared__ float hpart[8][2][64];              // head partials
  __shared__ float thetaL[2][64];
  __shared__ float dtL[2];
  __shared__ float liftL[32 * 49];               // stride 49: bank-conflict-free
  __shared__ float u2yL[16 * 32];

  const int t = threadIdx.x;
  const int b0 = blockIdx.x * 2;
  const int j = t & 127;   // hidden unit
  const int q = t >> 7;    // k-slice [40q, 40q+40)
  const int tfe = *tf_p;

  // ---- register-resident gate weights: rows j, j+128, j+256; cols 40q..40q+39
  float wr[40], wz[40], wn[40];
  {
    const int jr = j, jz = j + 128, jn = j + 256;
#pragma unroll
    for (int cc = 0; cc < 40; ++cc) {
      int c = q * 40 + cc;
      if (c < 32) {
        wr[cc] = w_ih[jr * 32 + c];
        wz[cc] = w_ih[jz * 32 + c];
        wn[cc] = w_ih[jn * 32 + c];
      } else {
        wr[cc] = w_hh[jr * 128 + c - 32];
        wz[cc] = w_hh[jz * 128 + c - 32];
        wn[cc] = w_hh[jn * 128 + c - 32];
      }
    }
  }
  const int ho = t & 63;   // head output
  const int he = t >> 6;   // head k-slice [16he, 16he+16)
  float wh[16];
#pragma unroll
  for (int i = 0; i < 16; ++i) wh[i] = head_W[ho * 128 + he * 16 + i];

  float bR = 0, bZ = 0, bIn = 0, bHn = 0, hb = 0, lb = 0;
  if (t < 128) {
    bR = b_ih[j] + b_hh[j];
    bZ = b_ih[j + 128] + b_hh[j + 128];
    bIn = b_ih[j + 256];
    bHn = b_hh[j + 256];
    hb = head_b[ho];
  }
  if (t < 64) lb = lift_b[t & 31];

  for (int idx = t; idx < 32 * 48; idx += 512)
    liftL[(idx / 48) * 49 + (idx % 48)] = lift_W[idx];
  if (t < 512) {
    // u2y is 16*32 = 512 elements: one per thread
    u2yL[t] = u2y[t];
  }
  if (t < 128) {
    vecL[0][32 + j] = 0.0f;  // h0 = 0
    vecL[1][32 + j] = 0.0f;
  }

  float hreg[2] = {0.0f, 0.0f};
  float yreg = 0.0f;
  if (t < 64) {
    int bb = t >> 5, jj = t & 31;
    yreg = y0[(b0 + bb) * 32 + jj];
  }
  __syncthreads();

  for (int k = 0; k < 1024; ++k) {
    // ---- phase 1: stage u_k, dt_k, y_in (wave 0 only)
    if (t < 32) {
      int bb = t >> 4, i = t & 15;
      featL[bb][i] = u_seq[((b0 + bb) * 1024 + k) * 16 + i];
    }
    if (t >= 32 && t < 34) {
      dtL[t - 32] = dt_seq[(b0 + t - 32) * 1024 + k];
    }
    if (t < 64) {
      int bb = t >> 5, jj = t & 31;
      float yin = yreg;
      if (k > 0 && (k % tfe) == 0)
        yin = y_seq[((b0 + bb) * 1024 + (k - 1)) * 32 + jj];
      featL[bb][16 + jj] = yin;
    }
    __syncthreads();  // A

    // ---- phase 2: lift  x = silu(feat @ lift_W.T + lift_b)
    if (t < 64) {
      int bb = t >> 5, o = t & 31;
      float acc = lb;
#pragma unroll
      for (int i = 0; i < 48; ++i) acc += featL[bb][i] * liftL[o * 49 + i];
      vecL[bb][o] = acc * sigf(acc);
    }
    __syncthreads();  // B

    // ---- phase 3: gates  (all 512 threads, both batches)
    float accR[2], accZ[2], accN[2], accI[2];
#pragma unroll
    for (int bb = 0; bb < 2; ++bb) {
      float aR = 0.0f, aZ = 0.0f, aN = 0.0f, aI = 0.0f;
      const float4* v4 =
          reinterpret_cast<const float4*>(&vecL[bb][0]) + q * 10;
      if (q == 0) {
#pragma unroll
        for (int i = 0; i < 10; ++i) {
          float4 v = v4[i];
          DOT4(aR, v, wr, 4 * i)
          DOT4(aZ, v, wz, 4 * i)
          if (i < 8) {
            DOT4(aI, v, wn, 4 * i)   // x-part of n-gate (i_n)
          } else {
            DOT4(aN, v, wn, 4 * i)   // h-part of n-gate (h_n)
          }
        }
      } else {
#pragma unroll
        for (int i = 0; i < 10; ++i) {
          float4 v = v4[i];
          DOT4(aR, v, wr, 4 * i)
          DOT4(aZ, v, wz, 4 * i)
          DOT4(aN, v, wn, 4 * i)
        }
      }
      if (q > 0) {
        gpart[q - 1][bb][0][j] = aR;
        gpart[q - 1][bb][1][j] = aZ;
        gpart[q - 1][bb][2][j] = aN;
      } else {
        accR[bb] = aR;
        accZ[bb] = aZ;
        accN[bb] = aN;
        accI[bb] = aI;
      }
    }
    __syncthreads();  // C

    // ---- phase 4: GRU elementwise + h update (t<128)
    if (t < 128) {
#pragma unroll
      for (int bb = 0; bb < 2; ++bb) {
        float sR = accR[bb] + bR;
        float sZ = accZ[bb] + bZ;
        float sN = accN[bb] + bHn;  // h_n accumulator (+b_hh)
#pragma unroll
        for (int qq = 0; qq < 3; ++qq) {
          sR += gpart[qq][bb][0][j];
          sZ += gpart[qq][bb][1][j];
          sN += gpart[qq][bb][2][j];
        }
        float r = sigf(sR);
        float z = sigf(sZ);
        float n = tanh_fast(accI[bb] + bIn + r * sN);
        float hn = (1.0f - z) * n + z * hreg[bb];
        hreg[bb] = hn;
        vecL[bb][32 + j] = hn;
      }
    }
    __syncthreads();  // D

    // ---- phase 5: head partials (all threads)
#pragma unroll
    for (int bb = 0; bb < 2; ++bb) {
      const float4* h4 =
          reinterpret_cast<const float4*>(&vecL[bb][32]) + he * 4;
      float a = 0.0f;
#pragma unroll
      for (int i = 0; i < 4; ++i) {
        float4 v = h4[i];
        DOT4(a, v, wh, 4 * i)
      }
      hpart[he][bb][ho] = a;
    }
    __syncthreads();  // E

    // ---- phase 6: theta (t<128)
    if (t < 128) {
      int bb = t >> 6, o = t & 63;
      float s = hb;
#pragma unroll
      for (int e = 0; e < 8; ++e) s += hpart[e][bb][o];
      float th = 0.001f + 1.999f * sigf(s);
      thetaL[bb][o] = th;
      out_th[(size_t)((b0 + bb) * 1024 + k) * 64 + o] = th;
    }
    __syncthreads();  // F

    // ---- phase 7: jump + RK4 on y (wave 0 only; reads thetaL after F)
    if (t < 64) {
      int bb = t >> 5, jj = t & 31;
      float y = yreg;
#pragma unroll
      for (int i = 0; i < 16; ++i) y += featL[bb][i] * u2yL[i * 32 + jj];
      float a = thetaL[bb][jj];
      float b2 = thetaL[bb][32 + jj];
      float hdt = dtL[bb];
      float k1 = b2 - a * y;
      float k2 = b2 - a * (y + 0.5f * hdt * k1);
      float k3 = b2 - a * (y + 0.5f * hdt * k2);
      float k4 = b2 - a * (y + hdt * k3);
      y += hdt * (1.0f / 6.0f) * (k1 + 2.0f * k2 + 2.0f * k3 + k4);
      yreg = y;
      out_ys[(size_t)((b0 + bb) * 1024 + k) * 32 + jj] = y;
    }
    // no barrier: only wave 0 touches featL/dtL before next A; thetaL/hpart
    // rewritten only after multiple barriers next iteration.
  }
}

extern "C" void kernel_launch(void* const* d_in, const int* in_sizes, int n_in,
                              void* d_out, int out_size, void* d_ws,
                              size_t ws_size, hipStream_t stream) {
  (void)in_sizes; (void)n_in; (void)out_size; (void)d_ws; (void)ws_size;
  const float* y0     = (const float*)d_in[0];
  const float* u_seq  = (const float*)d_in[1];
  const float* dt_seq = (const float*)d_in[2];
  const float* y_seq  = (const float*)d_in[3];
  const float* u2y    = (const float*)d_in[4];
  const float* lift_W = (const float*)d_in[5];
  const float* lift_b = (const float*)d_in[6];
  const float* w_ih   = (const float*)d_in[7];
  const float* w_hh   = (const float*)d_in[8];
  const float* b_ih   = (const float*)d_in[9];
  const float* b_hh   = (const float*)d_in[10];
  const float* head_W = (const float*)d_in[11];
  const float* head_b = (const float*)d_in[12];
  const int*   tf_p   = (const int*)d_in[13];

  float* out_ys = (float*)d_out;
  float* out_th = out_ys + (size_t)512 * 1024 * 32;

  odernn_kernel<<<dim3(256), dim3(512), 0, stream>>>(
      y0, u_seq, dt_seq, y_seq, u2y, lift_W, lift_b, w_ih, w_hh, b_ih, b_hh,
      head_W, head_b, tf_p, out_ys, out_th);
}